// Round 1
// baseline (741.206 us; speedup 1.0000x reference)
//
#include <hip/hip_runtime.h>
#include <math.h>

// InfoNCE loss, K=3, SKIP=1, NEG=64
// Shapes: z,c: (64,256,14,14) f32; Wk: (3,256,256) f32; neg_idx_k: (rows*64,) i32
// rows_k = (14-(k+1))*14*64  -> 10752, 9856, 8960 (all divisible by 64; each
// 64-row tile shares one (h,w), b = row % 64).

#define C_DIM 256

// WkT[k][c*256+o] = Wk[k][o*256+c]  (coalesced read, scattered write; 768KB total)
__global__ void wk_transpose_kernel(const float* __restrict__ Wk, float* __restrict__ WkT) {
    int i = blockIdx.x * 256 + threadIdx.x;   // 0..196607
    int k   = i >> 16;
    int rem = i & 65535;
    int o   = rem >> 8;
    int c   = rem & 255;
    WkT[(k << 16) + (c << 8) + o] = Wk[i];
}

__global__ void zero_acc_kernel(float* acc) {
    if (threadIdx.x < 3) acc[threadIdx.x] = 0.f;
}

// ztwk[row][o] = sum_c z[b, c, h + koff, w] * Wk[o][c],  row = (h*14+w)*64 + b
// Block: 64 rows x 64 outs, 256 threads, 4x4 microtile. grid = (Hp*14, 4).
__global__ __launch_bounds__(256)
void proj_kernel(const float* __restrict__ z, const float* __restrict__ wkt,
                 float* __restrict__ ztwk, int koff) {
    __shared__ float zs[16][64];
    __shared__ float wks[16][64];
    const int tid = threadIdx.x;
    const int tx = tid & 15;        // out group
    const int ty = tid >> 4;        // row group
    const int hw = blockIdx.x;      // h*14 + w
    const int h = hw / 14, w = hw % 14;
    const int o0 = blockIdx.y << 6;
    const int zh = h + koff;
    const float* zbase = z + zh * 14 + w;   // + (b*256 + c)*196

    float acc[4][4];
    #pragma unroll
    for (int i = 0; i < 4; i++)
        #pragma unroll
        for (int j = 0; j < 4; j++) acc[i][j] = 0.f;

    for (int c0 = 0; c0 < 256; c0 += 16) {
        __syncthreads();
        #pragma unroll
        for (int u = 0; u < 4; u++) {
            int e  = tid + (u << 8);
            int cc = e >> 6;
            int r  = e & 63;               // r == b, also == o for wks
            zs[cc][r]  = zbase[(r * 256 + c0 + cc) * 196];
            wks[cc][r] = wkt[(c0 + cc) * 256 + o0 + r];
        }
        __syncthreads();
        #pragma unroll
        for (int cc = 0; cc < 16; cc++) {
            float4 a  = *reinterpret_cast<const float4*>(&zs[cc][ty << 2]);
            float4 bb = *reinterpret_cast<const float4*>(&wks[cc][tx << 2]);
            float av[4] = {a.x, a.y, a.z, a.w};
            float bv[4] = {bb.x, bb.y, bb.z, bb.w};
            #pragma unroll
            for (int i = 0; i < 4; i++)
                #pragma unroll
                for (int j = 0; j < 4; j++)
                    acc[i][j] = fmaf(av[i], bv[j], acc[i][j]);
        }
    }
    const int row0 = hw << 6;
    #pragma unroll
    for (int i = 0; i < 4; i++) {
        int r = (ty << 2) + i;
        float4 v = make_float4(acc[i][0], acc[i][1], acc[i][2], acc[i][3]);
        *reinterpret_cast<float4*>(&ztwk[(size_t)(row0 + r) * 256 + o0 + (tx << 2)]) = v;
    }
}

// One block per row. 65 dots of length 256 (j=0: main; j>=1: gathered negs),
// then softmax over 65, take -log(p0 + 1e-11), atomicAdd into acc[kk].
__global__ __launch_bounds__(256)
void loss_kernel(const float* __restrict__ cin, const float* __restrict__ flat,
                 const int* __restrict__ neg_idx, float* __restrict__ acc, int kk) {
    __shared__ float ctxs[256];
    __shared__ float logits[65];
    const int row = blockIdx.x;
    const int b  = row & 63;
    const int wh = row >> 6;
    const int w = wh % 14;
    const int h = wh / 14;
    const int tid = threadIdx.x;
    // ctx[c] = c[b, c, h, w]
    ctxs[tid] = cin[(b * 256 + tid) * 196 + h * 14 + w];
    __syncthreads();

    const int wave = tid >> 6, lane = tid & 63;
    const float4 cx = *reinterpret_cast<const float4*>(&ctxs[lane << 2]);
    for (int j = wave; j <= 64; j += 4) {
        int idx = (j == 0) ? row : neg_idx[row * 64 + j - 1];
        const float4 f = *reinterpret_cast<const float4*>(&flat[(size_t)idx * 256 + (lane << 2)]);
        float v = f.x * cx.x + f.y * cx.y + f.z * cx.z + f.w * cx.w;
        #pragma unroll
        for (int off = 32; off >= 1; off >>= 1) v += __shfl_down(v, off);
        if (lane == 0) logits[j] = v;
    }
    __syncthreads();

    if (tid < 64) {
        float main_l = logits[0];
        float x = logits[1 + tid];
        float m = x;
        #pragma unroll
        for (int off = 32; off >= 1; off >>= 1) m = fmaxf(m, __shfl_xor(m, off));
        m = fmaxf(m, main_l);
        float e = __expf(x - m);
        #pragma unroll
        for (int off = 32; off >= 1; off >>= 1) e += __shfl_xor(e, off);
        float em = __expf(main_l - m);
        float p0 = em / (e + em);
        if (tid == 0) atomicAdd(&acc[kk], -logf(p0 + 1e-11f));
    }
}

__global__ void combine_kernel(const float* __restrict__ acc, float* __restrict__ out) {
    out[0] = (acc[0] * (1.f / 10752.f) +
              acc[1] * (1.f / 9856.f) +
              acc[2] * (1.f / 8960.f)) * (1.f / 3.f);
}

extern "C" void kernel_launch(void* const* d_in, const int* in_sizes, int n_in,
                              void* d_out, int out_size, void* d_ws, size_t ws_size,
                              hipStream_t stream) {
    const float* z  = (const float*)d_in[0];
    const float* c  = (const float*)d_in[1];
    const float* Wk = (const float*)d_in[2];
    const int* negs[3] = {(const int*)d_in[3], (const int*)d_in[4], (const int*)d_in[5]};
    float* out = (float*)d_out;

    // workspace layout
    float* ztwk = (float*)d_ws;               // 10752*256 floats (reused per k)
    float* wkt  = ztwk + 10752 * 256;         // 3*65536 floats
    float* acc  = wkt + 3 * 65536;            // 3 floats

    zero_acc_kernel<<<1, 64, 0, stream>>>(acc);
    wk_transpose_kernel<<<768, 256, 0, stream>>>(Wk, wkt);

    const int HpA[3] = {12, 11, 10};
    for (int k = 1; k <= 3; ++k) {
        int Hp = HpA[k - 1];
        int rows = Hp * 14 * 64;
        dim3 pg(Hp * 14, 4);
        proj_kernel<<<pg, 256, 0, stream>>>(z, wkt + (k - 1) * 65536, ztwk, k + 1);
        loss_kernel<<<rows, 256, 0, stream>>>(c, ztwk, negs[k - 1], acc, k - 1);
    }
    combine_kernel<<<1, 1, 0, stream>>>(acc, out);
}

// Round 2
// 355.019 us; speedup vs baseline: 2.0878x; 2.0878x over previous
//
#include <hip/hip_runtime.h>
#include <math.h>

// InfoNCE loss, K=3, SKIP=1, NEG=64
// z,c: (64,256,14,14) f32; Wk: (3,256,256) f32; neg_idx_k: (rows_k*64,) i32
// rows_k = (14-(k+1))*14*64 -> 10752, 9856, 8960. row = (h*14+w)*64 + b.
//
// Pipeline: transpose z,c -> [hw][b][c] contiguous; Wk -> WkT; per k:
// proj GEMM (rows x 256 x 256) -> ztwk; loss per row -> rowloss;
// final grid-stride reduce -> out[0].

__global__ void zero_out_kernel(float* out) { out[0] = 0.f; }

// WkT[k][c*256+o] = Wk[k][o*256+c]
__global__ void wk_transpose_kernel(const float* __restrict__ Wk, float* __restrict__ WkT) {
    int i = blockIdx.x * 256 + threadIdx.x;   // 0..196607
    int k   = i >> 16;
    int rem = i & 65535;
    int o   = rem >> 8;
    int c   = rem & 255;
    WkT[(k << 16) + (c << 8) + o] = Wk[i];
}

// x[b][c][hw] (c-major, hw contiguous)  ->  xt[(hw*64+b)*256 + c]
// grid (64 b, 16 c-tiles), 256 threads. Coalesced read; 64B-segment writes.
__global__ __launch_bounds__(256)
void transpose_kernel(const float* __restrict__ x, float* __restrict__ xt) {
    __shared__ float tile[16][201];           // 201 pad: conflict-free phase-2 reads
    const int tid = threadIdx.x;
    const int b  = blockIdx.x;
    const int c0 = blockIdx.y << 4;
    for (int i = tid; i < 16 * 196; i += 256) {
        int cc = i / 196;
        int hw = i - cc * 196;
        tile[cc][hw] = x[(size_t)((b << 8) + c0 + cc) * 196 + hw];
    }
    __syncthreads();
    for (int i = tid; i < 196 * 16; i += 256) {
        int hw = i >> 4;
        int cc = i & 15;
        xt[(size_t)((hw << 6) + b) * 256 + c0 + cc] = tile[cc][hw];
    }
}

// ztwk[row][o] = sum_c zt[zrow][c] * WkT[c][o], zrow = row + koff*14*64.
// Block: 64 rows x 64 outs, 256 threads, 4x4 microtile. grid (Hp*14, 4).
__global__ __launch_bounds__(256)
void proj_kernel(const float* __restrict__ zt, const float* __restrict__ wkt,
                 float* __restrict__ ztwk, int koff) {
    __shared__ float zs[16][68];              // 68 pad: 16B-aligned b128, <=2-way bank
    __shared__ float wks[16][64];
    const int tid = threadIdx.x;
    const int tx = tid & 15;                  // out group
    const int ty = tid >> 4;                  // row group
    const int hw = blockIdx.x;
    const int o0 = blockIdx.y << 6;
    const int zrow0 = (hw + koff * 14) << 6;
    const int r4 = tid >> 2, q = tid & 3;     // staging map: thread -> (row, c-quad)

    float acc[4][4];
    #pragma unroll
    for (int i = 0; i < 4; i++)
        #pragma unroll
        for (int j = 0; j < 4; j++) acc[i][j] = 0.f;

    for (int c0 = 0; c0 < 256; c0 += 16) {
        __syncthreads();
        float4 v = *reinterpret_cast<const float4*>(
            &zt[(size_t)(zrow0 + r4) * 256 + c0 + (q << 2)]);
        zs[(q << 2) + 0][r4] = v.x;
        zs[(q << 2) + 1][r4] = v.y;
        zs[(q << 2) + 2][r4] = v.z;
        zs[(q << 2) + 3][r4] = v.w;
        #pragma unroll
        for (int u = 0; u < 4; u++) {
            int e  = tid + (u << 8);
            int cc = e >> 6;
            int r  = e & 63;
            wks[cc][r] = wkt[(c0 + cc) * 256 + o0 + r];
        }
        __syncthreads();
        #pragma unroll
        for (int cc = 0; cc < 16; cc++) {
            float4 a  = *reinterpret_cast<const float4*>(&zs[cc][ty << 2]);
            float4 bb = *reinterpret_cast<const float4*>(&wks[cc][tx << 2]);
            float av[4] = {a.x, a.y, a.z, a.w};
            float bv[4] = {bb.x, bb.y, bb.z, bb.w};
            #pragma unroll
            for (int i = 0; i < 4; i++)
                #pragma unroll
                for (int j = 0; j < 4; j++)
                    acc[i][j] = fmaf(av[i], bv[j], acc[i][j]);
        }
    }
    const int row0 = hw << 6;
    #pragma unroll
    for (int i = 0; i < 4; i++) {
        int r = (ty << 2) + i;
        float4 v = make_float4(acc[i][0], acc[i][1], acc[i][2], acc[i][3]);
        *reinterpret_cast<float4*>(&ztwk[(size_t)(row0 + r) * 256 + o0 + (tx << 2)]) = v;
    }
}

// One block per row. 65 dots of length 256, softmax over 65, per-row loss
// (pre-weighted) -> rowloss[row]. No global atomics.
__global__ __launch_bounds__(256)
void loss_kernel(const float* __restrict__ ct, const float* __restrict__ flat,
                 const int* __restrict__ neg_idx, float* __restrict__ rowloss,
                 float wk) {
    __shared__ float logits[65];
    __shared__ int negs_s[64];
    const int row = blockIdx.x;
    const int tid = threadIdx.x;
    const int lane = tid & 63, w = tid >> 6;

    if (tid < 64) negs_s[tid] = neg_idx[(row << 6) + tid];
    const float4 cx = *reinterpret_cast<const float4*>(
        &ct[(size_t)row * 256 + (lane << 2)]);
    __syncthreads();

    // wave w handles j = w, w+4, ..., unrolled 4-wide for load/shuffle ILP
    #pragma unroll
    for (int batch = 0; batch < 4; ++batch) {
        int   idxv[4];
        float part[4];
        #pragma unroll
        for (int u = 0; u < 4; ++u) {
            int j = w + (((batch << 2) + u) << 2);
            idxv[u] = (j == 0) ? row : negs_s[j - 1];
        }
        #pragma unroll
        for (int u = 0; u < 4; ++u) {
            const float4 f = *reinterpret_cast<const float4*>(
                &flat[(size_t)idxv[u] * 256 + (lane << 2)]);
            part[u] = f.x * cx.x + f.y * cx.y + f.z * cx.z + f.w * cx.w;
        }
        #pragma unroll
        for (int off = 32; off >= 1; off >>= 1)
            #pragma unroll
            for (int u = 0; u < 4; ++u)
                part[u] += __shfl_down(part[u], off);
        if (lane == 0) {
            #pragma unroll
            for (int u = 0; u < 4; ++u)
                logits[w + (((batch << 2) + u) << 2)] = part[u];
        }
    }
    if (w == 0) {   // j = 64
        int idx = negs_s[63];
        const float4 f = *reinterpret_cast<const float4*>(
            &flat[(size_t)idx * 256 + (lane << 2)]);
        float v = f.x * cx.x + f.y * cx.y + f.z * cx.z + f.w * cx.w;
        #pragma unroll
        for (int off = 32; off >= 1; off >>= 1) v += __shfl_down(v, off);
        if (lane == 0) logits[64] = v;
    }
    __syncthreads();

    if (tid < 64) {
        float main_l = logits[0];
        float x = logits[1 + tid];
        float m = x;
        #pragma unroll
        for (int off = 32; off >= 1; off >>= 1) m = fmaxf(m, __shfl_xor(m, off));
        m = fmaxf(m, main_l);
        float e = __expf(x - m);
        #pragma unroll
        for (int off = 32; off >= 1; off >>= 1) e += __shfl_xor(e, off);
        float em = __expf(main_l - m);
        float p0 = em / (e + em);
        if (tid == 0) rowloss[row] = -logf(p0 + 1e-11f) * wk;
    }
}

// Sum rowloss (3 segments of 10752/9856/8960 in a [3][10752] layout) -> out[0]
__global__ __launch_bounds__(256)
void reduce_kernel(const float* __restrict__ rl, float* __restrict__ out) {
    float s = 0.f;
    const int stride = gridDim.x * blockDim.x;
    for (int i = blockIdx.x * blockDim.x + threadIdx.x; i < 29568; i += stride) {
        // segments: [0,10752) -> k0; [10752,20608) -> k1 (base 10752);
        // [20608,29568) -> k2 (base 21504) => j = i + 896
        int j = (i < 20608) ? i : i + 896;
        s += rl[j];
    }
    #pragma unroll
    for (int off = 32; off >= 1; off >>= 1) s += __shfl_xor(s, off);
    if ((threadIdx.x & 63) == 0) atomicAdd(out, s);
}

extern "C" void kernel_launch(void* const* d_in, const int* in_sizes, int n_in,
                              void* d_out, int out_size, void* d_ws, size_t ws_size,
                              hipStream_t stream) {
    const float* z  = (const float*)d_in[0];
    const float* c  = (const float*)d_in[1];
    const float* Wk = (const float*)d_in[2];
    const int* negs[3] = {(const int*)d_in[3], (const int*)d_in[4], (const int*)d_in[5]};
    float* out = (float*)d_out;

    // workspace layout (floats): zt 3211264 | ct 3211264 | wkt 196608 |
    // ztwk 2752512 | rowloss 32256   -> ~37.6 MB total
    float* zt      = (float*)d_ws;
    float* ct      = zt + 196 * 64 * 256;
    float* wkt     = ct + 196 * 64 * 256;
    float* ztwk    = wkt + 3 * 65536;
    float* rowloss = ztwk + 10752 * 256;

    zero_out_kernel<<<1, 1, 0, stream>>>(out);
    transpose_kernel<<<dim3(64, 16), 256, 0, stream>>>(z, zt);
    transpose_kernel<<<dim3(64, 16), 256, 0, stream>>>(c, ct);
    wk_transpose_kernel<<<768, 256, 0, stream>>>(Wk, wkt);

    const int HpA[3] = {12, 11, 10};
    for (int k = 1; k <= 3; ++k) {
        int Hp = HpA[k - 1];
        int rows = Hp * 14 * 64;
        dim3 pg(Hp * 14, 4);
        proj_kernel<<<pg, 256, 0, stream>>>(zt, wkt + (k - 1) * 65536, ztwk, k + 1);
        loss_kernel<<<rows, 256, 0, stream>>>(ct, ztwk, negs[k - 1],
                                              rowloss + (k - 1) * 10752,
                                              1.f / (3.f * rows));
    }
    reduce_kernel<<<32, 256, 0, stream>>>(rowloss, out);
}

// Round 3
// 304.127 us; speedup vs baseline: 2.4372x; 1.1673x over previous
//
#include <hip/hip_runtime.h>
#include <math.h>

// InfoNCE loss, K=3, SKIP=1, NEG=64
// z,c: (64,256,14,14) f32; Wk: (3,256,256) f32; neg_idx_k: (rows_k*64,) i32
// rows_k = 10752, 9856, 8960. row = (h*14+w)*64 + b.
//
// bf16 pipeline: zt[hw*64+b][c] bf16, wkb[k][o][c] bf16 (no transpose — MFMA
// B-frag wants K-contiguous per n), ct fp32. proj = MFMA bf16 GEMM writing
// ztwk bf16 (5.5 MB -> L2-resident for the gather). loss gathers bf16 rows.

typedef short bf16x8 __attribute__((ext_vector_type(8)));
typedef float f32x4 __attribute__((ext_vector_type(4)));

static __device__ __forceinline__ unsigned short f2bf(float f) {
    union { float f; unsigned int u; } x; x.f = f;
    unsigned int r = x.u + 0x7fffu + ((x.u >> 16) & 1u);   // RNE
    return (unsigned short)(r >> 16);
}
static __device__ __forceinline__ float bflo(unsigned int u) {
    union { unsigned int u; float f; } x; x.u = u << 16; return x.f;
}
static __device__ __forceinline__ float bfhi(unsigned int u) {
    union { unsigned int u; float f; } x; x.u = u & 0xffff0000u; return x.f;
}

__global__ void zero_out_kernel(float* out) { out[0] = 0.f; }

// Wk f32 -> bf16, same [k][o][c] layout (K-contiguous rows for MFMA B-frags)
__global__ void cast_wk_kernel(const float* __restrict__ Wk, unsigned short* __restrict__ wkb) {
    int i = blockIdx.x * 256 + threadIdx.x;   // 0..196607
    wkb[i] = f2bf(Wk[i]);
}

// c[b][ch][hw] f32 -> ct[(hw*64+b)*256 + ch] f32
__global__ __launch_bounds__(256)
void transpose_c_kernel(const float* __restrict__ x, float* __restrict__ xt) {
    __shared__ float tile[16][201];
    const int tid = threadIdx.x;
    const int b  = blockIdx.x;
    const int c0 = blockIdx.y << 4;
    for (int i = tid; i < 16 * 196; i += 256) {
        int cc = i / 196;
        int hw = i - cc * 196;
        tile[cc][hw] = x[(size_t)((b << 8) + c0 + cc) * 196 + hw];
    }
    __syncthreads();
    for (int i = tid; i < 196 * 16; i += 256) {
        int hw = i >> 4;
        int cc = i & 15;
        xt[(size_t)((hw << 6) + b) * 256 + c0 + cc] = tile[cc][hw];
    }
}

// z[b][ch][hw] f32 -> zt[(hw*64+b)*256 + ch] bf16
__global__ __launch_bounds__(256)
void transpose_z_kernel(const float* __restrict__ x, unsigned short* __restrict__ xt) {
    __shared__ float tile[16][201];
    const int tid = threadIdx.x;
    const int b  = blockIdx.x;
    const int c0 = blockIdx.y << 4;
    for (int i = tid; i < 16 * 196; i += 256) {
        int cc = i / 196;
        int hw = i - cc * 196;
        tile[cc][hw] = x[(size_t)((b << 8) + c0 + cc) * 196 + hw];
    }
    __syncthreads();
    for (int i = tid; i < 196 * 16; i += 256) {
        int hw = i >> 4;
        int cc = i & 15;
        xt[(size_t)((hw << 6) + b) * 256 + c0 + cc] = f2bf(tile[cc][hw]);
    }
}

// ztwk[row][o] = sum_c zt[zrow][c] * wk[o][c]   (bf16 in, bf16 out, f32 acc)
// grid (Hp*14, 4), 256 threads = 4 waves. Block tile M=64 rows x N=64 outs;
// wave w: M64 x N16 (4 MFMA 16x16x32 acc tiles), K-loop 8 x 32.
// A-frag: A[m=lane&15][k=(lane>>4)*8+j] (K-contiguous 16B load from zt row).
// B-frag: B[k=(lane>>4)*8+j][n=lane&15] <- wk[n][k] K-contiguous 16B load.
// D: col(n)=lane&15, row(m)=(lane>>4)*4+reg.
__global__ __launch_bounds__(256)
void proj_mfma_kernel(const unsigned short* __restrict__ zt,
                      const unsigned short* __restrict__ wkb,
                      unsigned short* __restrict__ ztwk, int koff) {
    const int tid = threadIdx.x;
    const int wv = tid >> 6, lane = tid & 63;
    const int m  = lane & 15, kq = lane >> 4;       // kq in 0..3
    const int hw = blockIdx.x;
    const int o0 = (blockIdx.y << 6) + (wv << 4);
    const int row0  = hw << 6;
    const int zrow0 = row0 + ((koff * 14) << 6);

    f32x4 acc[4] = {{0.f,0.f,0.f,0.f},{0.f,0.f,0.f,0.f},
                    {0.f,0.f,0.f,0.f},{0.f,0.f,0.f,0.f}};
    const unsigned short* a0 = zt  + (size_t)(zrow0 + m) * 256 + (kq << 3);
    const unsigned short* b0 = wkb + (size_t)(o0 + m)    * 256 + (kq << 3);

    #pragma unroll
    for (int kk = 0; kk < 256; kk += 32) {
        bf16x8 bf = *reinterpret_cast<const bf16x8*>(b0 + kk);
        #pragma unroll
        for (int mt = 0; mt < 4; mt++) {
            bf16x8 af = *reinterpret_cast<const bf16x8*>(a0 + (mt << 12) + kk); // mt*16 rows * 256
            acc[mt] = __builtin_amdgcn_mfma_f32_16x16x32_bf16(af, bf, acc[mt], 0, 0, 0);
        }
    }
    #pragma unroll
    for (int mt = 0; mt < 4; mt++) {
        #pragma unroll
        for (int r = 0; r < 4; r++) {
            int row = row0 + (mt << 4) + (kq << 2) + r;
            ztwk[(size_t)row * 256 + o0 + m] = f2bf(acc[mt][r]);
        }
    }
}

// One block per row. 65 dots of length 256 over bf16 gathered rows,
// softmax over 65, pre-weighted per-row loss -> rowloss[row].
__global__ __launch_bounds__(256)
void loss_kernel(const float* __restrict__ ct, const unsigned short* __restrict__ flat,
                 const int* __restrict__ neg_idx, float* __restrict__ rowloss,
                 float wk) {
    __shared__ float logits[65];
    __shared__ int negs_s[64];
    const int row = blockIdx.x;
    const int tid = threadIdx.x;
    const int lane = tid & 63, w = tid >> 6;

    if (tid < 64) negs_s[tid] = neg_idx[(row << 6) + tid];
    const float4 cx = *reinterpret_cast<const float4*>(
        &ct[(size_t)row * 256 + (lane << 2)]);
    const uint2* fr = reinterpret_cast<const uint2*>(flat);   // 64 uint2 per row
    __syncthreads();

    #pragma unroll
    for (int batch = 0; batch < 4; ++batch) {
        int   idxv[4];
        float part[4];
        #pragma unroll
        for (int u = 0; u < 4; ++u) {
            int j = w + (((batch << 2) + u) << 2);
            idxv[u] = (j == 0) ? row : negs_s[j - 1];
        }
        #pragma unroll
        for (int u = 0; u < 4; ++u) {
            uint2 f = fr[((size_t)idxv[u] << 6) + lane];
            part[u] = fmaf(bflo(f.x), cx.x, fmaf(bfhi(f.x), cx.y,
                      fmaf(bflo(f.y), cx.z, bfhi(f.y) * cx.w)));
        }
        #pragma unroll
        for (int off = 32; off >= 1; off >>= 1)
            #pragma unroll
            for (int u = 0; u < 4; ++u)
                part[u] += __shfl_down(part[u], off);
        if (lane == 0) {
            #pragma unroll
            for (int u = 0; u < 4; ++u)
                logits[w + (((batch << 2) + u) << 2)] = part[u];
        }
    }
    if (w == 0) {   // j = 64
        uint2 f = fr[((size_t)negs_s[63] << 6) + lane];
        float v = fmaf(bflo(f.x), cx.x, fmaf(bfhi(f.x), cx.y,
                  fmaf(bflo(f.y), cx.z, bfhi(f.y) * cx.w)));
        #pragma unroll
        for (int off = 32; off >= 1; off >>= 1) v += __shfl_down(v, off);
        if (lane == 0) logits[64] = v;
    }
    __syncthreads();

    if (tid < 64) {
        float main_l = logits[0];
        float x = logits[1 + tid];
        float m = x;
        #pragma unroll
        for (int off = 32; off >= 1; off >>= 1) m = fmaxf(m, __shfl_xor(m, off));
        m = fmaxf(m, main_l);
        float e = __expf(x - m);
        #pragma unroll
        for (int off = 32; off >= 1; off >>= 1) e += __shfl_xor(e, off);
        float em = __expf(main_l - m);
        float p0 = em / (e + em);
        if (tid == 0) rowloss[row] = -logf(p0 + 1e-11f) * wk;
    }
}

// Sum rowloss ([3][10752] layout, segments 10752/9856/8960) -> out[0]
__global__ __launch_bounds__(256)
void reduce_kernel(const float* __restrict__ rl, float* __restrict__ out) {
    float s = 0.f;
    const int stride = gridDim.x * blockDim.x;
    for (int i = blockIdx.x * blockDim.x + threadIdx.x; i < 29568; i += stride) {
        int j = (i < 20608) ? i : i + 896;
        s += rl[j];
    }
    #pragma unroll
    for (int off = 32; off >= 1; off >>= 1) s += __shfl_xor(s, off);
    if ((threadIdx.x & 63) == 0) atomicAdd(out, s);
}

extern "C" void kernel_launch(void* const* d_in, const int* in_sizes, int n_in,
                              void* d_out, int out_size, void* d_ws, size_t ws_size,
                              hipStream_t stream) {
    const float* z  = (const float*)d_in[0];
    const float* c  = (const float*)d_in[1];
    const float* Wk = (const float*)d_in[2];
    const int* negs[3] = {(const int*)d_in[3], (const int*)d_in[4], (const int*)d_in[5]};
    float* out = (float*)d_out;

    // workspace layout (bytes): ct f32 12.25MB | zt bf16 6.125MB |
    // wkb bf16 384KB | ztwk bf16 5.25MB | rowloss f32 126KB
    char* p = (char*)d_ws;
    float*          ct      = (float*)p;            p += (size_t)196 * 64 * 256 * 4;
    unsigned short* zt      = (unsigned short*)p;   p += (size_t)196 * 64 * 256 * 2;
    unsigned short* wkb     = (unsigned short*)p;   p += (size_t)3 * 65536 * 2;
    unsigned short* ztwk    = (unsigned short*)p;   p += (size_t)10752 * 256 * 2;
    float*          rowloss = (float*)p;

    zero_out_kernel<<<1, 1, 0, stream>>>(out);
    cast_wk_kernel<<<768, 256, 0, stream>>>(Wk, wkb);
    transpose_z_kernel<<<dim3(64, 16), 256, 0, stream>>>(z, zt);
    transpose_c_kernel<<<dim3(64, 16), 256, 0, stream>>>(c, ct);

    const int HpA[3] = {12, 11, 10};
    for (int k = 1; k <= 3; ++k) {
        int Hp = HpA[k - 1];
        int rows = Hp * 14 * 64;
        dim3 pg(Hp * 14, 4);
        proj_mfma_kernel<<<pg, 256, 0, stream>>>(zt, wkb + (k - 1) * 65536, ztwk, k + 1);
        loss_kernel<<<rows, 256, 0, stream>>>(ct, ztwk, negs[k - 1],
                                              rowloss + (k - 1) * 10752,
                                              1.f / (3.f * rows));
    }
    reduce_kernel<<<32, 256, 0, stream>>>(rowloss, out);
}

// Round 4
// 262.506 us; speedup vs baseline: 2.8236x; 1.1586x over previous
//
#include <hip/hip_runtime.h>
#include <math.h>

// InfoNCE loss, K=3, SKIP=1, NEG=64
// z,c: (64,256,14,14) f32; Wk: (3,256,256) f32; neg_idx_k: (rows_k*64,) i32
// rows_k = 10752, 9856, 8960. row = (h*14+w)*64 + b.
//
// All-bf16 pipeline: zt/ct[(hw*64+b)][c] bf16; wkb[k][o][c] bf16;
// proj = single merged MFMA GEMM dispatch -> ztwk[k] bf16 (L2-resident);
// loss = one WAVE per row: gathered neg rows are MFMA A-frags, ctx broadcast
// in all 16 B-columns -> 40 MFMAs produce all 65 logits; softmax via 2 shuffles.

typedef short bf16x8 __attribute__((ext_vector_type(8)));
typedef float f32x4 __attribute__((ext_vector_type(4)));

static __device__ __forceinline__ unsigned short f2bf(float f) {
    union { float f; unsigned int u; } x; x.f = f;
    unsigned int r = x.u + 0x7fffu + ((x.u >> 16) & 1u);   // RNE
    return (unsigned short)(r >> 16);
}

__global__ void zero_out_kernel(float* out) { out[0] = 0.f; }

// Wk f32 -> bf16, same [k][o][c] layout (K-contiguous rows for MFMA B-frags)
__global__ void cast_wk_kernel(const float* __restrict__ Wk, unsigned short* __restrict__ wkb) {
    int i = blockIdx.x * 256 + threadIdx.x;   // 0..196607
    wkb[i] = f2bf(Wk[i]);
}

// x[b][ch][hw] f32 -> xt[(hw*64+b)*256 + ch] bf16
__global__ __launch_bounds__(256)
void transpose_bf16_kernel(const float* __restrict__ x, unsigned short* __restrict__ xt) {
    __shared__ float tile[16][201];
    const int tid = threadIdx.x;
    const int b  = blockIdx.x;
    const int c0 = blockIdx.y << 4;
    for (int i = tid; i < 16 * 196; i += 256) {
        int cc = i / 196;
        int hw = i - cc * 196;
        tile[cc][hw] = x[(size_t)((b << 8) + c0 + cc) * 196 + hw];
    }
    __syncthreads();
    for (int i = tid; i < 196 * 16; i += 256) {
        int hw = i >> 4;
        int cc = i & 15;
        xt[(size_t)((hw << 6) + b) * 256 + c0 + cc] = f2bf(tile[cc][hw]);
    }
}

// ztwk[k][row][o] = sum_c zt[zrow][c] * wk[k][o][c]  (bf16 in/out, f32 acc)
// One dispatch for all 3 k: grid (462, 4). x<168:k0, x<322:k1, else k2.
// Block: M=64 rows x N=64 outs, 4 waves, wave = M64xN16, K-loop 8x32.
// Epilogue: stage C in LDS, store 16B-coalesced.
__global__ __launch_bounds__(256)
void proj_mfma_kernel(const unsigned short* __restrict__ zt,
                      const unsigned short* __restrict__ wkb,
                      unsigned short* __restrict__ ztwk) {
    __shared__ __align__(16) unsigned short cs[64][72];  // pad 72: spread kq banks
    int x = blockIdx.x;
    int k, hw;
    if (x < 168)      { k = 0; hw = x; }
    else if (x < 322) { k = 1; hw = x - 168; }
    else              { k = 2; hw = x - 322; }
    const unsigned short* wkp = wkb + (k << 16);
    unsigned short* zo = ztwk + (size_t)k * 10752 * 256;

    const int tid = threadIdx.x;
    const int wv = tid >> 6, lane = tid & 63;
    const int m = lane & 15, kq = lane >> 4;
    const int o0 = blockIdx.y << 6;
    const int oW = o0 + (wv << 4);
    const int row0  = hw << 6;
    const int zrow0 = row0 + (((k + 2) * 14) << 6);   // h' = h + (k_idx+2)

    f32x4 acc[4] = {};
    const unsigned short* a0 = zt  + (size_t)(zrow0 + m) * 256 + (kq << 3);
    const unsigned short* b0 = wkp + (size_t)(oW + m)    * 256 + (kq << 3);

    #pragma unroll
    for (int kk = 0; kk < 256; kk += 32) {
        bf16x8 bf = *reinterpret_cast<const bf16x8*>(b0 + kk);
        #pragma unroll
        for (int mt = 0; mt < 4; mt++) {
            bf16x8 af = *reinterpret_cast<const bf16x8*>(a0 + (mt << 12) + kk);
            acc[mt] = __builtin_amdgcn_mfma_f32_16x16x32_bf16(af, bf, acc[mt], 0, 0, 0);
        }
    }
    #pragma unroll
    for (int mt = 0; mt < 4; mt++)
        #pragma unroll
        for (int r = 0; r < 4; r++)
            cs[(mt << 4) + (kq << 2) + r][(wv << 4) + m] = f2bf(acc[mt][r]);
    __syncthreads();
    #pragma unroll
    for (int it = 0; it < 2; ++it) {
        int cidx = (it << 8) + tid;       // 0..511 chunks of 16B
        int r = cidx >> 3, off = cidx & 7;
        int4 v = *reinterpret_cast<const int4*>(&cs[r][off << 3]);
        *reinterpret_cast<int4*>(&zo[(size_t)(row0 + r) * 256 + o0 + (off << 3)]) = v;
    }
}

// One wave per row. Slots 0..79: 0 = main (self), 1..64 = negs, 65..79 = pad.
// 5 M-tiles of 16 gathered rows -> A-frags; ctx (bf16, LDS) broadcast in all
// B columns. D: slot = mt*16 + kq*4 + r. Softmax over slots 0..64.
__global__ __launch_bounds__(256)
void loss_mfma_kernel(const unsigned short* __restrict__ ct,
                      const unsigned short* __restrict__ flat,
                      const int* __restrict__ neg_idx,
                      float* __restrict__ rowloss, float wk) {
    __shared__ __align__(16) unsigned short ctx_s[4][256];
    const int tid = threadIdx.x;
    const int wv = tid >> 6, lane = tid & 63;
    const int m = lane & 15, kq = lane >> 4;
    const int row = (blockIdx.x << 2) + wv;

    // stage ctx row (bf16) into this wave's LDS slab
    uint2 cv = *reinterpret_cast<const uint2*>(ct + (size_t)row * 256 + (lane << 2));
    *reinterpret_cast<uint2*>(&ctx_s[wv][lane << 2]) = cv;

    // gather-row indices for this lane's m across the 5 M-tiles
    const int* nb = neg_idx + ((size_t)row << 6);
    const unsigned short* ap[5];
    #pragma unroll
    for (int mt = 0; mt < 5; ++mt) {
        int slot = (mt << 4) + m;
        int j = slot - 1;
        int jc = j < 0 ? 0 : (j > 63 ? 63 : j);
        int t = nb[jc];
        int idx = (slot == 0 || slot > 64) ? row : t;
        ap[mt] = flat + (size_t)idx * 256 + (kq << 3);
    }
    __syncthreads();

    f32x4 acc[5] = {};
    const unsigned short* cp = &ctx_s[wv][kq << 3];
    #pragma unroll
    for (int kk = 0; kk < 8; ++kk) {
        bf16x8 bfrag = *reinterpret_cast<const bf16x8*>(cp + (kk << 5));
        #pragma unroll
        for (int mt = 0; mt < 5; ++mt) {
            bf16x8 af = *reinterpret_cast<const bf16x8*>(ap[mt] + (kk << 5));
            acc[mt] = __builtin_amdgcn_mfma_f32_16x16x32_bf16(af, bfrag, acc[mt], 0, 0, 0);
        }
    }

    // softmax over slots 0..64. mt<4 all valid; mt=4 valid only (kq==0, r==0).
    float m_l = -1e30f;
    #pragma unroll
    for (int mt = 0; mt < 4; ++mt)
        #pragma unroll
        for (int r = 0; r < 4; ++r) m_l = fmaxf(m_l, acc[mt][r]);
    if (kq == 0) m_l = fmaxf(m_l, acc[4][0]);
    m_l = fmaxf(m_l, __shfl_xor(m_l, 16));
    m_l = fmaxf(m_l, __shfl_xor(m_l, 32));

    float s_l = 0.f;
    #pragma unroll
    for (int mt = 0; mt < 4; ++mt)
        #pragma unroll
        for (int r = 0; r < 4; ++r) s_l += __expf(acc[mt][r] - m_l);
    if (kq == 0) s_l += __expf(acc[4][0] - m_l);
    s_l += __shfl_xor(s_l, 16);
    s_l += __shfl_xor(s_l, 32);

    float main_l = __shfl(acc[0][0], 0);   // lane 0: kq=0, reg 0 -> slot 0
    if (lane == 0) {
        float p0 = __expf(main_l - m_l) / s_l;
        rowloss[row] = -logf(p0 + 1e-11f) * wk;
    }
}

// Sum rowloss[0..29568) -> out[0]
__global__ __launch_bounds__(256)
void reduce_kernel(const float* __restrict__ rl, float* __restrict__ out) {
    float s = 0.f;
    const int stride = gridDim.x * blockDim.x;
    for (int i = blockIdx.x * blockDim.x + threadIdx.x; i < 29568; i += stride)
        s += rl[i];
    #pragma unroll
    for (int off = 32; off >= 1; off >>= 1) s += __shfl_xor(s, off);
    if ((threadIdx.x & 63) == 0) atomicAdd(out, s);
}

extern "C" void kernel_launch(void* const* d_in, const int* in_sizes, int n_in,
                              void* d_out, int out_size, void* d_ws, size_t ws_size,
                              hipStream_t stream) {
    const float* z  = (const float*)d_in[0];
    const float* c  = (const float*)d_in[1];
    const float* Wk = (const float*)d_in[2];
    const int* negs[3] = {(const int*)d_in[3], (const int*)d_in[4], (const int*)d_in[5]};
    float* out = (float*)d_out;

    // workspace (bytes): ct bf16 6.125MB | zt bf16 6.125MB | wkb bf16 384KB |
    // ztwk bf16 [3][10752][256] 15.75MB | rowloss f32 115KB  (~28.5MB)
    char* p = (char*)d_ws;
    unsigned short* ct      = (unsigned short*)p;   p += (size_t)196 * 64 * 256 * 2;
    unsigned short* zt      = (unsigned short*)p;   p += (size_t)196 * 64 * 256 * 2;
    unsigned short* wkb     = (unsigned short*)p;   p += (size_t)3 * 65536 * 2;
    unsigned short* ztwk    = (unsigned short*)p;   p += (size_t)3 * 10752 * 256 * 2;
    float*          rowloss = (float*)p;

    zero_out_kernel<<<1, 1, 0, stream>>>(out);
    cast_wk_kernel<<<768, 256, 0, stream>>>(Wk, wkb);
    transpose_bf16_kernel<<<dim3(64, 16), 256, 0, stream>>>(z, zt);
    transpose_bf16_kernel<<<dim3(64, 16), 256, 0, stream>>>(c, ct);

    proj_mfma_kernel<<<dim3(462, 4), 256, 0, stream>>>(zt, wkb, ztwk);

    const int rowsA[3] = {10752, 9856, 8960};
    const int baseA[3] = {0, 10752, 20608};
    for (int k = 0; k < 3; ++k) {
        loss_mfma_kernel<<<rowsA[k] >> 2, 256, 0, stream>>>(
            ct, ztwk + (size_t)k * 10752 * 256, negs[k],
            rowloss + baseA[k], 1.f / (3.f * rowsA[k]));
    }
    reduce_kernel<<<32, 256, 0, stream>>>(rowloss, out);
}

// Round 5
// 262.503 us; speedup vs baseline: 2.8236x; 1.0000x over previous
//
#include <hip/hip_runtime.h>
#include <math.h>

// InfoNCE loss, K=3, SKIP=1, NEG=64
// z,c: (64,256,14,14) f32; Wk: (3,256,256) f32; neg_idx_k: (rows_k*64,) i32
// rows_k = 10752, 9856, 8960. row = (h*14+w)*64 + b.
//
// Pipeline: zt[(hw*64+b)][c] bf16; wkb[k][o][c] bf16; proj = merged MFMA GEMM
// -> ztwk fp8 e4m3 (2.6 MB/k: fits per-XCD L2, halves gather lines);
// ct fp8. loss = one wave per row, fp8 MFMA: gathered neg rows are A-frags,
// ctx broadcast in all 16 B-columns; softmax via 2 shuffles.

typedef short bf16x8 __attribute__((ext_vector_type(8)));
typedef float f32x4 __attribute__((ext_vector_type(4)));

static __device__ __forceinline__ unsigned short f2bf(float f) {
    union { float f; unsigned int u; } x; x.f = f;
    unsigned int r = x.u + 0x7fffu + ((x.u >> 16) & 1u);   // RNE
    return (unsigned short)(r >> 16);
}

// float -> OCP e4m3fn (RNE, saturate to 448, subnormals handled)
static __device__ __forceinline__ unsigned char f2e4m3(float f) {
    union { float f; unsigned int u; } x; x.f = f;
    unsigned int s = (x.u >> 24) & 0x80u;
    float af = fabsf(f);
    if (af > 448.f) af = 448.f;
    x.f = af;
    unsigned int u = x.u;
    int e = (int)(u >> 23) - 127;
    unsigned int out;
    if (af == 0.f) {
        out = 0u;
    } else if (e < -6) {
        int mq = (int)rintf(af * 512.f);          // multiples of 2^-9
        out = (mq >= 8) ? 0x08u : (unsigned int)mq;
    } else {
        unsigned int r = u + 0x7FFFFu + ((u >> 20) & 1u);  // RNE, drop 20 bits
        int e2 = (int)(r >> 23) - 127;
        if (e2 > 8) out = 0x7Eu;                  // 448
        else out = (unsigned int)(((e2 + 7) << 3) | ((r >> 20) & 7u));
    }
    return (unsigned char)(s | out);
}

__global__ void zero_out_kernel(float* out) { out[0] = 0.f; }

// Wk f32 -> bf16, [k][o][c] (K-contiguous rows for MFMA B-frags)
__global__ void cast_wk_kernel(const float* __restrict__ Wk, unsigned short* __restrict__ wkb) {
    int i = blockIdx.x * 256 + threadIdx.x;   // 0..196607
    wkb[i] = f2bf(Wk[i]);
}

// z[b][ch][hw] f32 -> zt[(hw*64+b)*256 + ch] bf16
__global__ __launch_bounds__(256)
void transpose_z_kernel(const float* __restrict__ x, unsigned short* __restrict__ xt) {
    __shared__ float tile[16][201];
    const int tid = threadIdx.x;
    const int b  = blockIdx.x;
    const int c0 = blockIdx.y << 4;
    for (int i = tid; i < 16 * 196; i += 256) {
        int cc = i / 196;
        int hw = i - cc * 196;
        tile[cc][hw] = x[(size_t)((b << 8) + c0 + cc) * 196 + hw];
    }
    __syncthreads();
    for (int i = tid; i < 196 * 16; i += 256) {
        int hw = i >> 4;
        int cc = i & 15;
        xt[(size_t)((hw << 6) + b) * 256 + c0 + cc] = f2bf(tile[cc][hw]);
    }
}

// c[b][ch][hw] f32 -> ct8[(hw*64+b)*256 + ch] fp8 e4m3
__global__ __launch_bounds__(256)
void transpose_c8_kernel(const float* __restrict__ x, unsigned char* __restrict__ xt) {
    __shared__ float tile[16][201];
    const int tid = threadIdx.x;
    const int b  = blockIdx.x;
    const int c0 = blockIdx.y << 4;
    for (int i = tid; i < 16 * 196; i += 256) {
        int cc = i / 196;
        int hw = i - cc * 196;
        tile[cc][hw] = x[(size_t)((b << 8) + c0 + cc) * 196 + hw];
    }
    __syncthreads();
    for (int i = tid; i < 196 * 16; i += 256) {
        int hw = i >> 4;
        int cc = i & 15;
        xt[(size_t)((hw << 6) + b) * 256 + c0 + cc] = f2e4m3(tile[cc][hw]);
    }
}

// ztwk8[k][row][o] = fp8(sum_c zt[zrow][c] * wk[k][o][c])  (bf16 MFMA, f32 acc)
// One dispatch for all 3 k: grid (462, 4). x<168:k0, x<322:k1, else k2.
// Block: M=64 rows x N=64 outs, 4 waves, wave = M64xN16, K-loop 8x32.
// Epilogue: stage fp8 C in LDS, store 16B-coalesced.
__global__ __launch_bounds__(256)
void proj_mfma_kernel(const unsigned short* __restrict__ zt,
                      const unsigned short* __restrict__ wkb,
                      unsigned char* __restrict__ ztwk) {
    __shared__ __align__(16) unsigned char cs[64][80];   // 80: 16B-aligned rows
    int x = blockIdx.x;
    int k, hw;
    if (x < 168)      { k = 0; hw = x; }
    else if (x < 322) { k = 1; hw = x - 168; }
    else              { k = 2; hw = x - 322; }
    const unsigned short* wkp = wkb + (k << 16);
    unsigned char* zo = ztwk + (size_t)k * 10752 * 256;

    const int tid = threadIdx.x;
    const int wv = tid >> 6, lane = tid & 63;
    const int m = lane & 15, kq = lane >> 4;
    const int o0 = blockIdx.y << 6;
    const int oW = o0 + (wv << 4);
    const int row0  = hw << 6;
    const int zrow0 = row0 + (((k + 2) * 14) << 6);   // h' = h + (k_idx+2)

    f32x4 acc[4] = {};
    const unsigned short* a0 = zt  + (size_t)(zrow0 + m) * 256 + (kq << 3);
    const unsigned short* b0 = wkp + (size_t)(oW + m)    * 256 + (kq << 3);

    #pragma unroll
    for (int kk = 0; kk < 256; kk += 32) {
        bf16x8 bf = *reinterpret_cast<const bf16x8*>(b0 + kk);
        #pragma unroll
        for (int mt = 0; mt < 4; mt++) {
            bf16x8 af = *reinterpret_cast<const bf16x8*>(a0 + (mt << 12) + kk);
            acc[mt] = __builtin_amdgcn_mfma_f32_16x16x32_bf16(af, bf, acc[mt], 0, 0, 0);
        }
    }
    #pragma unroll
    for (int mt = 0; mt < 4; mt++)
        #pragma unroll
        for (int r = 0; r < 4; r++)
            cs[(mt << 4) + (kq << 2) + r][(wv << 4) + m] = f2e4m3(acc[mt][r]);
    __syncthreads();
    // 64 rows x 64 B per block = 4096 B = 256 threads x 16 B
    {
        int r = tid >> 2, off = tid & 3;
        int4 v = *reinterpret_cast<const int4*>(&cs[r][off << 4]);
        *reinterpret_cast<int4*>(&zo[(size_t)(row0 + r) * 256 + o0 + (off << 4)]) = v;
    }
}

// One wave per row. Slots 0..79: 0 = main (self), 1..64 = negs, 65..79 = pad.
// 5 M-tiles of 16 gathered fp8 rows -> A-frags (8 B/lane); ctx fp8 (LDS)
// broadcast in all B columns. D: slot = mt*16 + kq*4 + r. Softmax over 0..64.
__global__ __launch_bounds__(256)
void loss_mfma_kernel(const unsigned char* __restrict__ ct8,
                      const unsigned char* __restrict__ flat8,
                      const int* __restrict__ neg_idx,
                      float* __restrict__ rowloss, float wk) {
    __shared__ __align__(16) unsigned char ctx_s[4][256];
    const int tid = threadIdx.x;
    const int wv = tid >> 6, lane = tid & 63;
    const int m = lane & 15, kq = lane >> 4;
    const int row = (blockIdx.x << 2) + wv;

    // stage ctx row (256 B) into this wave's LDS slab
    unsigned int cv = *reinterpret_cast<const unsigned int*>(
        ct8 + (size_t)row * 256 + (lane << 2));
    *reinterpret_cast<unsigned int*>(&ctx_s[wv][lane << 2]) = cv;

    const int* nb = neg_idx + ((size_t)row << 6);
    const unsigned char* ap[5];
    #pragma unroll
    for (int mt = 0; mt < 5; ++mt) {
        int slot = (mt << 4) + m;
        int j = slot - 1;
        int jc = j < 0 ? 0 : (j > 63 ? 63 : j);
        int t = nb[jc];
        int idx = (slot == 0 || slot > 64) ? row : t;
        ap[mt] = flat8 + (size_t)idx * 256 + (kq << 3);
    }
    __syncthreads();

    f32x4 acc[5] = {};
    const unsigned char* cp = &ctx_s[wv][kq << 3];
    #pragma unroll
    for (int kk = 0; kk < 8; ++kk) {
        long long bfrag = *reinterpret_cast<const long long*>(cp + (kk << 5));
        #pragma unroll
        for (int mt = 0; mt < 5; ++mt) {
            long long af = *reinterpret_cast<const long long*>(ap[mt] + (kk << 5));
            acc[mt] = __builtin_amdgcn_mfma_f32_16x16x32_fp8_fp8(af, bfrag, acc[mt], 0, 0, 0);
        }
    }

    // softmax over slots 0..64. mt<4 all valid; mt=4 valid only slot 64 (kq==0,r==0).
    float m_l = -1e30f;
    #pragma unroll
    for (int mt = 0; mt < 4; ++mt)
        #pragma unroll
        for (int r = 0; r < 4; ++r) m_l = fmaxf(m_l, acc[mt][r]);
    if (kq == 0) m_l = fmaxf(m_l, acc[4][0]);
    m_l = fmaxf(m_l, __shfl_xor(m_l, 16));
    m_l = fmaxf(m_l, __shfl_xor(m_l, 32));

    float s_l = 0.f;
    #pragma unroll
    for (int mt = 0; mt < 4; ++mt)
        #pragma unroll
        for (int r = 0; r < 4; ++r) s_l += __expf(acc[mt][r] - m_l);
    if (kq == 0) s_l += __expf(acc[4][0] - m_l);
    s_l += __shfl_xor(s_l, 16);
    s_l += __shfl_xor(s_l, 32);

    float main_l = __shfl(acc[0][0], 0);   // lane 0: slot 0
    if (lane == 0) {
        float p0 = __expf(main_l - m_l) / s_l;
        rowloss[row] = -logf(p0 + 1e-11f) * wk;
    }
}

// Sum rowloss[0..29568) -> out[0]
__global__ __launch_bounds__(256)
void reduce_kernel(const float* __restrict__ rl, float* __restrict__ out) {
    float s = 0.f;
    const int stride = gridDim.x * blockDim.x;
    for (int i = blockIdx.x * blockDim.x + threadIdx.x; i < 29568; i += stride)
        s += rl[i];
    #pragma unroll
    for (int off = 32; off >= 1; off >>= 1) s += __shfl_xor(s, off);
    if ((threadIdx.x & 63) == 0) atomicAdd(out, s);
}

extern "C" void kernel_launch(void* const* d_in, const int* in_sizes, int n_in,
                              void* d_out, int out_size, void* d_ws, size_t ws_size,
                              hipStream_t stream) {
    const float* z  = (const float*)d_in[0];
    const float* c  = (const float*)d_in[1];
    const float* Wk = (const float*)d_in[2];
    const int* negs[3] = {(const int*)d_in[3], (const int*)d_in[4], (const int*)d_in[5]};
    float* out = (float*)d_out;

    // workspace (bytes): zt bf16 6.4MB | wkb bf16 384KB | ct8 fp8 3.2MB |
    // ztwk8 fp8 [3][10752][256] 8.26MB | rowloss f32 118KB  (~18.4MB)
    char* p = (char*)d_ws;
    unsigned short* zt      = (unsigned short*)p;   p += (size_t)196 * 64 * 256 * 2;
    unsigned short* wkb     = (unsigned short*)p;   p += (size_t)3 * 65536 * 2;
    unsigned char*  ct8     = (unsigned char*)p;    p += (size_t)196 * 64 * 256;
    unsigned char*  ztwk8   = (unsigned char*)p;    p += (size_t)3 * 10752 * 256;
    float*          rowloss = (float*)p;

    zero_out_kernel<<<1, 1, 0, stream>>>(out);
    cast_wk_kernel<<<768, 256, 0, stream>>>(Wk, wkb);
    transpose_z_kernel<<<dim3(64, 16), 256, 0, stream>>>(z, zt);
    transpose_c8_kernel<<<dim3(64, 16), 256, 0, stream>>>(c, ct8);

    proj_mfma_kernel<<<dim3(462, 4), 256, 0, stream>>>(zt, wkb, ztwk8);

    const int rowsA[3] = {10752, 9856, 8960};
    const int baseA[3] = {0, 10752, 20608};
    for (int k = 0; k < 3; ++k) {
        loss_mfma_kernel<<<rowsA[k] >> 2, 256, 0, stream>>>(
            ct8, ztwk8 + (size_t)k * 10752 * 256, negs[k],
            rowloss + baseA[k], 1.f / (3.f * rowsA[k]));
    }
    reduce_kernel<<<32, 256, 0, stream>>>(rowloss, out);
}

// Round 6
// 195.267 us; speedup vs baseline: 3.7959x; 1.3443x over previous
//
#include <hip/hip_runtime.h>
#include <math.h>

// InfoNCE loss, K=3, SKIP=1, NEG=64
// z,c: (64,256,14,14) f32; Wk: (3,256,256) f32; neg_idx_k: (rows_k*64,) i32
// rows_k = 10752, 9856, 8960. row = (h*14+w)*64 + b.
//
// Pipeline: zt[(hw*64+b)][c] bf16; wkb[k][o][c] bf16; proj merged MFMA GEMM
// -> ztwk fp8 e4m3 (2.6 MB/k, L2-resident). loss (single dispatch, all k):
// one wave per row; 65 rows gathered COALESCED (64 lanes x 4B = one row per
// instruction, 4 segments vs 16 scattered) into a per-wave LDS slab
// (272 B stride: balanced banks for ds_read_b64 A-frags); fp8 MFMA computes
// all 65 logits; softmax via 2 shuffles.

typedef short bf16x8 __attribute__((ext_vector_type(8)));
typedef float f32x4 __attribute__((ext_vector_type(4)));

static __device__ __forceinline__ unsigned short f2bf(float f) {
    union { float f; unsigned int u; } x; x.f = f;
    unsigned int r = x.u + 0x7fffu + ((x.u >> 16) & 1u);   // RNE
    return (unsigned short)(r >> 16);
}

// float -> OCP e4m3fn (RNE, saturate to 448, subnormals handled)
static __device__ __forceinline__ unsigned char f2e4m3(float f) {
    union { float f; unsigned int u; } x; x.f = f;
    unsigned int s = (x.u >> 24) & 0x80u;
    float af = fabsf(f);
    if (af > 448.f) af = 448.f;
    x.f = af;
    unsigned int u = x.u;
    int e = (int)(u >> 23) - 127;
    unsigned int out;
    if (af == 0.f) {
        out = 0u;
    } else if (e < -6) {
        int mq = (int)rintf(af * 512.f);          // multiples of 2^-9
        out = (mq >= 8) ? 0x08u : (unsigned int)mq;
    } else {
        unsigned int r = u + 0x7FFFFu + ((u >> 20) & 1u);  // RNE, drop 20 bits
        int e2 = (int)(r >> 23) - 127;
        if (e2 > 8) out = 0x7Eu;                  // 448
        else out = (unsigned int)(((e2 + 7) << 3) | ((r >> 20) & 7u));
    }
    return (unsigned char)(s | out);
}

__global__ void zero_out_kernel(float* out) { out[0] = 0.f; }

// Wk f32 -> bf16, [k][o][c] (K-contiguous rows for MFMA B-frags)
__global__ void cast_wk_kernel(const float* __restrict__ Wk, unsigned short* __restrict__ wkb) {
    int i = blockIdx.x * 256 + threadIdx.x;   // 0..196607
    wkb[i] = f2bf(Wk[i]);
}

// z[b][ch][hw] f32 -> zt[(hw*64+b)*256 + ch] bf16
__global__ __launch_bounds__(256)
void transpose_z_kernel(const float* __restrict__ x, unsigned short* __restrict__ xt) {
    __shared__ float tile[16][201];
    const int tid = threadIdx.x;
    const int b  = blockIdx.x;
    const int c0 = blockIdx.y << 4;
    for (int i = tid; i < 16 * 196; i += 256) {
        int cc = i / 196;
        int hw = i - cc * 196;
        tile[cc][hw] = x[(size_t)((b << 8) + c0 + cc) * 196 + hw];
    }
    __syncthreads();
    for (int i = tid; i < 196 * 16; i += 256) {
        int hw = i >> 4;
        int cc = i & 15;
        xt[(size_t)((hw << 6) + b) * 256 + c0 + cc] = f2bf(tile[cc][hw]);
    }
}

// c[b][ch][hw] f32 -> ct8[(hw*64+b)*256 + ch] fp8 e4m3
__global__ __launch_bounds__(256)
void transpose_c8_kernel(const float* __restrict__ x, unsigned char* __restrict__ xt) {
    __shared__ float tile[16][201];
    const int tid = threadIdx.x;
    const int b  = blockIdx.x;
    const int c0 = blockIdx.y << 4;
    for (int i = tid; i < 16 * 196; i += 256) {
        int cc = i / 196;
        int hw = i - cc * 196;
        tile[cc][hw] = x[(size_t)((b << 8) + c0 + cc) * 196 + hw];
    }
    __syncthreads();
    for (int i = tid; i < 196 * 16; i += 256) {
        int hw = i >> 4;
        int cc = i & 15;
        xt[(size_t)((hw << 6) + b) * 256 + c0 + cc] = f2e4m3(tile[cc][hw]);
    }
}

// ztwk8[k][row][o] = fp8(sum_c zt[zrow][c] * wk[k][o][c])  (bf16 MFMA, f32 acc)
// One dispatch for all 3 k: grid (462, 4). Block: M=64 x N=64, 4 waves.
__global__ __launch_bounds__(256)
void proj_mfma_kernel(const unsigned short* __restrict__ zt,
                      const unsigned short* __restrict__ wkb,
                      unsigned char* __restrict__ ztwk) {
    __shared__ __align__(16) unsigned char cs[64][80];
    int x = blockIdx.x;
    int k, hw;
    if (x < 168)      { k = 0; hw = x; }
    else if (x < 322) { k = 1; hw = x - 168; }
    else              { k = 2; hw = x - 322; }
    const unsigned short* wkp = wkb + (k << 16);
    unsigned char* zo = ztwk + (size_t)k * 10752 * 256;

    const int tid = threadIdx.x;
    const int wv = tid >> 6, lane = tid & 63;
    const int m = lane & 15, kq = lane >> 4;
    const int o0 = blockIdx.y << 6;
    const int oW = o0 + (wv << 4);
    const int row0  = hw << 6;
    const int zrow0 = row0 + (((k + 2) * 14) << 6);   // h' = h + (k_idx+2)

    f32x4 acc[4] = {};
    const unsigned short* a0 = zt  + (size_t)(zrow0 + m) * 256 + (kq << 3);
    const unsigned short* b0 = wkp + (size_t)(oW + m)    * 256 + (kq << 3);

    #pragma unroll
    for (int kk = 0; kk < 256; kk += 32) {
        bf16x8 bf = *reinterpret_cast<const bf16x8*>(b0 + kk);
        #pragma unroll
        for (int mt = 0; mt < 4; mt++) {
            bf16x8 af = *reinterpret_cast<const bf16x8*>(a0 + (mt << 12) + kk);
            acc[mt] = __builtin_amdgcn_mfma_f32_16x16x32_bf16(af, bf, acc[mt], 0, 0, 0);
        }
    }
    #pragma unroll
    for (int mt = 0; mt < 4; mt++)
        #pragma unroll
        for (int r = 0; r < 4; r++)
            cs[(mt << 4) + (kq << 2) + r][(wv << 4) + m] = f2e4m3(acc[mt][r]);
    __syncthreads();
    {
        int r = tid >> 2, off = tid & 3;
        int4 v = *reinterpret_cast<const int4*>(&cs[r][off << 4]);
        *reinterpret_cast<int4*>(&zo[(size_t)(row0 + r) * 256 + o0 + (off << 4)]) = v;
    }
}

// Single dispatch for all 3 k. One wave per row-task; 2 waves (128 thr)/block.
// Phase 1: coalesced gather of 65 fp8 rows (self + 64 negs) into LDS slab.
// Phase 2: fp8 MFMA (A = gathered rows from LDS, B = ctx broadcast), softmax.
#define ROWB 272   // LDS row stride: 68 dwords -> balanced banks for b64 reads
__global__ __launch_bounds__(128, 2)
void loss_mfma_kernel(const unsigned char* __restrict__ ct8,
                      const unsigned char* __restrict__ ztwk8,
                      const int* __restrict__ n0, const int* __restrict__ n1,
                      const int* __restrict__ n2, float* __restrict__ rowloss) {
    __shared__ __align__(16) unsigned char slab[2][65 * ROWB];
    __shared__ __align__(16) unsigned char ctx_s[2][256];
    const int tid = threadIdx.x;
    const int wv = tid >> 6, lane = tid & 63;
    const int m = lane & 15, kq = lane >> 4;

    // block -> (k, local row pair). blocks: 5376 / 4928 / 4480
    int x = blockIdx.x;
    int k;
    const int* nb_base;
    if (x < 5376)       { k = 0; nb_base = n0; }
    else if (x < 10304) { k = 1; nb_base = n1; x -= 5376; }
    else                { k = 2; nb_base = n2; x -= 10304; }
    const int row = (x << 1) + wv;
    const unsigned char* flat8 = ztwk8 + (size_t)k * 10752 * 256;
    const float wk = (k == 0) ? (1.f / (3.f * 10752.f))
                   : (k == 1) ? (1.f / (3.f * 9856.f))
                              : (1.f / (3.f * 8960.f));
    const int rbase = (k == 0) ? 0 : (k == 1) ? 10752 : 20608;
    unsigned char* sl = &slab[wv][0];

    // stage ctx row (256 B, coalesced)
    unsigned int cv = *reinterpret_cast<const unsigned int*>(
        ct8 + (size_t)row * 256 + (lane << 2));
    *reinterpret_cast<unsigned int*>(&ctx_s[wv][lane << 2]) = cv;

    const int myidx = nb_base[(row << 6) + lane];

    // gather: each iteration = one full row, 64 lanes x 4 B, coalesced
    {
        const unsigned int* g0 = reinterpret_cast<const unsigned int*>(
            flat8 + (size_t)row * 256);
        *reinterpret_cast<unsigned int*>(&sl[(size_t)0 * ROWB + (lane << 2)]) = g0[lane];
    }
    #pragma unroll
    for (int j = 1; j <= 64; ++j) {
        int idx = __shfl(myidx, j - 1);
        const unsigned int* g = reinterpret_cast<const unsigned int*>(
            flat8 + (size_t)idx * 256);
        *reinterpret_cast<unsigned int*>(&sl[(size_t)j * ROWB + (lane << 2)]) = g[lane];
    }
    __syncthreads();

    // MFMA phase: 5 M-tiles x 8 K-steps; A from LDS slab, B = ctx broadcast
    f32x4 acc[5] = {};
    const unsigned char* cp = &ctx_s[wv][kq << 3];
    int slotoff[5];
    #pragma unroll
    for (int mt = 0; mt < 5; ++mt) {
        int slot = (mt << 4) + m;
        if (slot > 64) slot = 64;           // pad slots read slot 64 (ignored)
        slotoff[mt] = slot * ROWB + (kq << 3);
    }
    #pragma unroll
    for (int kk = 0; kk < 8; ++kk) {
        long long bfrag = *reinterpret_cast<const long long*>(cp + (kk << 5));
        #pragma unroll
        for (int mt = 0; mt < 5; ++mt) {
            long long af = *reinterpret_cast<const long long*>(
                sl + slotoff[mt] + (kk << 5));
            acc[mt] = __builtin_amdgcn_mfma_f32_16x16x32_fp8_fp8(af, bfrag, acc[mt], 0, 0, 0);
        }
    }

    // softmax over slots 0..64 (slot = mt*16 + kq*4 + r)
    float m_l = -1e30f;
    #pragma unroll
    for (int mt = 0; mt < 4; ++mt)
        #pragma unroll
        for (int r = 0; r < 4; ++r) m_l = fmaxf(m_l, acc[mt][r]);
    if (kq == 0) m_l = fmaxf(m_l, acc[4][0]);
    m_l = fmaxf(m_l, __shfl_xor(m_l, 16));
    m_l = fmaxf(m_l, __shfl_xor(m_l, 32));

    float s_l = 0.f;
    #pragma unroll
    for (int mt = 0; mt < 4; ++mt)
        #pragma unroll
        for (int r = 0; r < 4; ++r) s_l += __expf(acc[mt][r] - m_l);
    if (kq == 0) s_l += __expf(acc[4][0] - m_l);
    s_l += __shfl_xor(s_l, 16);
    s_l += __shfl_xor(s_l, 32);

    float main_l = __shfl(acc[0][0], 0);   // lane 0: slot 0
    if (lane == 0) {
        float p0 = __expf(main_l - m_l) / s_l;
        rowloss[rbase + row] = -logf(p0 + 1e-11f) * wk;
    }
}

// Sum rowloss[0..29568) -> out[0]
__global__ __launch_bounds__(256)
void reduce_kernel(const float* __restrict__ rl, float* __restrict__ out) {
    float s = 0.f;
    const int stride = gridDim.x * blockDim.x;
    for (int i = blockIdx.x * blockDim.x + threadIdx.x; i < 29568; i += stride)
        s += rl[i];
    #pragma unroll
    for (int off = 32; off >= 1; off >>= 1) s += __shfl_xor(s, off);
    if ((threadIdx.x & 63) == 0) atomicAdd(out, s);
}

extern "C" void kernel_launch(void* const* d_in, const int* in_sizes, int n_in,
                              void* d_out, int out_size, void* d_ws, size_t ws_size,
                              hipStream_t stream) {
    const float* z  = (const float*)d_in[0];
    const float* c  = (const float*)d_in[1];
    const float* Wk = (const float*)d_in[2];
    const int* negs[3] = {(const int*)d_in[3], (const int*)d_in[4], (const int*)d_in[5]};
    float* out = (float*)d_out;

    // workspace: zt bf16 6.4MB | wkb bf16 384KB | ct8 fp8 3.2MB |
    // ztwk8 fp8 [3][10752][256] 8.26MB | rowloss f32 118KB
    char* p = (char*)d_ws;
    unsigned short* zt      = (unsigned short*)p;   p += (size_t)196 * 64 * 256 * 2;
    unsigned short* wkb     = (unsigned short*)p;   p += (size_t)3 * 65536 * 2;
    unsigned char*  ct8     = (unsigned char*)p;    p += (size_t)196 * 64 * 256;
    unsigned char*  ztwk8   = (unsigned char*)p;    p += (size_t)3 * 10752 * 256;
    float*          rowloss = (float*)p;

    zero_out_kernel<<<1, 1, 0, stream>>>(out);
    cast_wk_kernel<<<768, 256, 0, stream>>>(Wk, wkb);
    transpose_z_kernel<<<dim3(64, 16), 256, 0, stream>>>(z, zt);
    transpose_c8_kernel<<<dim3(64, 16), 256, 0, stream>>>(c, ct8);

    proj_mfma_kernel<<<dim3(462, 4), 256, 0, stream>>>(zt, wkb, ztwk8);

    loss_mfma_kernel<<<14784, 128, 0, stream>>>(ct8, ztwk8, negs[0], negs[1],
                                                negs[2], rowloss);
    reduce_kernel<<<32, 256, 0, stream>>>(rowloss, out);
}

// Round 8
// 161.438 us; speedup vs baseline: 4.5913x; 1.2095x over previous
//
#include <hip/hip_runtime.h>
#include <math.h>

// InfoNCE loss, K=3, SKIP=1, NEG=64
// z,c: (64,256,14,14) f32; Wk: (3,256,256) f32; neg_idx_k: (rows_k*64,) i32
// rows_k = 10752, 9856, 8960. row = (h*14+w)*64 + b.
//
// Pipeline: zt[(hw*64+b)][c] bf16; wkb[k][o][c] bf16; proj = LDS-staged MFMA
// GEMM -> ztwk fp8 e4m3 (L2-resident). loss = 2-wave cooperative block per
// row: 65 rows DMA'd to LDS via global_load_lds (all loads in flight), fp8
// MFMA computes logits, cross-wave softmax.
//
// R7 bug fixed here: proj frag offsets were fp8-scaled byte shifts on bf16
// data (kq<<3 / kk<<5 bytes instead of 16/64 B) + PSTR 520 broke b128
// alignment. Frag pointers are element-typed now; PSTR = 544 (16B-aligned).

typedef short bf16x8 __attribute__((ext_vector_type(8)));
typedef float f32x4 __attribute__((ext_vector_type(4)));

static __device__ __forceinline__ unsigned short f2bf(float f) {
    union { float f; unsigned int u; } x; x.f = f;
    unsigned int r = x.u + 0x7fffu + ((x.u >> 16) & 1u);   // RNE
    return (unsigned short)(r >> 16);
}

// float -> OCP e4m3fn (RNE, saturate to 448, subnormals handled)
static __device__ __forceinline__ unsigned char f2e4m3(float f) {
    union { float f; unsigned int u; } x; x.f = f;
    unsigned int s = (x.u >> 24) & 0x80u;
    float af = fabsf(f);
    if (af > 448.f) af = 448.f;
    x.f = af;
    unsigned int u = x.u;
    int e = (int)(u >> 23) - 127;
    unsigned int out;
    if (af == 0.f) {
        out = 0u;
    } else if (e < -6) {
        int mq = (int)rintf(af * 512.f);          // multiples of 2^-9
        out = (mq >= 8) ? 0x08u : (unsigned int)mq;
    } else {
        unsigned int r = u + 0x7FFFFu + ((u >> 20) & 1u);  // RNE, drop 20 bits
        int e2 = (int)(r >> 23) - 127;
        if (e2 > 8) out = 0x7Eu;                  // 448
        else out = (unsigned int)(((e2 + 7) << 3) | ((r >> 20) & 7u));
    }
    return (unsigned char)(s | out);
}

// async global->LDS DMA: per-lane global addr, dest = uniform base + lane*4
static __device__ __forceinline__ void gload_lds4(const void* g, void* l) {
    __builtin_amdgcn_global_load_lds(
        (const __attribute__((address_space(1))) void*)g,
        (__attribute__((address_space(3))) void*)l, 4, 0, 0);
}

__global__ void zero_out_kernel(float* out) { out[0] = 0.f; }

// Wk f32 -> bf16, [k][o][c] (K-contiguous rows for MFMA B-frags)
__global__ void cast_wk_kernel(const float* __restrict__ Wk, unsigned short* __restrict__ wkb) {
    int i = blockIdx.x * 256 + threadIdx.x;   // 0..196607
    wkb[i] = f2bf(Wk[i]);
}

// z[b][ch][hw] f32 -> zt[(hw*64+b)*256 + ch] bf16
__global__ __launch_bounds__(256)
void transpose_z_kernel(const float* __restrict__ x, unsigned short* __restrict__ xt) {
    __shared__ float tile[16][201];
    const int tid = threadIdx.x;
    const int b  = blockIdx.x;
    const int c0 = blockIdx.y << 4;
    for (int i = tid; i < 16 * 196; i += 256) {
        int cc = i / 196;
        int hw = i - cc * 196;
        tile[cc][hw] = x[(size_t)((b << 8) + c0 + cc) * 196 + hw];
    }
    __syncthreads();
    for (int i = tid; i < 196 * 16; i += 256) {
        int hw = i >> 4;
        int cc = i & 15;
        xt[(size_t)((hw << 6) + b) * 256 + c0 + cc] = f2bf(tile[cc][hw]);
    }
}

// c[b][ch][hw] f32 -> ct8[(hw*64+b)*256 + ch] fp8 e4m3
__global__ __launch_bounds__(256)
void transpose_c8_kernel(const float* __restrict__ x, unsigned char* __restrict__ xt) {
    __shared__ float tile[16][201];
    const int tid = threadIdx.x;
    const int b  = blockIdx.x;
    const int c0 = blockIdx.y << 4;
    for (int i = tid; i < 16 * 196; i += 256) {
        int cc = i / 196;
        int hw = i - cc * 196;
        tile[cc][hw] = x[(size_t)((b << 8) + c0 + cc) * 196 + hw];
    }
    __syncthreads();
    for (int i = tid; i < 196 * 16; i += 256) {
        int hw = i >> 4;
        int cc = i & 15;
        xt[(size_t)((hw << 6) + b) * 256 + c0 + cc] = f2e4m3(tile[cc][hw]);
    }
}

// proj: ztwk8[k][row][o] = fp8(sum_c zt[zrow][c] * wk[k][o][c])
// Tile M=64 x N=32, grid (462, 8). A tile = 64 contiguous zt rows (32 KB),
// B tile = 32 contiguous wkb rows (16 KB), coalesced b128 stage into padded
// LDS (row stride 544 B, 16B-aligned), frags from LDS, fp8 epilogue via LDS.
#define PSTR 544
__global__ __launch_bounds__(256)
void proj_mfma_kernel(const unsigned short* __restrict__ zt,
                      const unsigned short* __restrict__ wkb,
                      unsigned char* __restrict__ ztwk) {
    __shared__ __align__(16) unsigned char smem[(64 + 32) * PSTR];  // 52224 B
    unsigned char* smA = smem;
    unsigned char* smB = smem + 64 * PSTR;

    int x = blockIdx.x;
    int k, hw;
    if (x < 168)      { k = 0; hw = x; }
    else if (x < 322) { k = 1; hw = x - 168; }
    else              { k = 2; hw = x - 322; }
    const int o0 = blockIdx.y << 5;                    // 32 outs per block
    const int row0  = hw << 6;
    const int zrow0 = row0 + (((k + 2) * 14) << 6);    // h' = h + (k_idx+2)
    unsigned char* zo = ztwk + (size_t)k * 10752 * 256;

    const int tid = threadIdx.x;
    const unsigned char* zsrc = (const unsigned char*)(zt + (size_t)zrow0 * 256);
    const unsigned char* bsrc = (const unsigned char*)(wkb + ((size_t)k << 16) + o0 * 256);

    #pragma unroll
    for (int i = 0; i < 8; ++i) {          // A: 32 KB contiguous
        int sb = ((i << 8) + tid) << 4;
        int r = sb >> 9, off = sb & 511;
        *(int4*)(smA + r * PSTR + off) = *(const int4*)(zsrc + sb);
    }
    #pragma unroll
    for (int i = 0; i < 4; ++i) {          // B: 16 KB contiguous
        int sb = ((i << 8) + tid) << 4;
        int r = sb >> 9, off = sb & 511;
        *(int4*)(smB + r * PSTR + off) = *(const int4*)(bsrc + sb);
    }
    __syncthreads();

    const int wv = tid >> 6, lane = tid & 63;
    const int m = lane & 15, kq = lane >> 4;
    f32x4 acc[2] = {};
    // element-typed frag pointers: + kq*8 elements (16 B), + kk*32 elements
    const unsigned short* aP  = (const unsigned short*)(smA + (size_t)((wv << 4) + m) * PSTR) + (kq << 3);
    const unsigned short* bP0 = (const unsigned short*)(smB + (size_t)m * PSTR) + (kq << 3);
    const unsigned short* bP1 = (const unsigned short*)(smB + (size_t)(16 + m) * PSTR) + (kq << 3);
    #pragma unroll
    for (int kk = 0; kk < 256; kk += 32) {
        bf16x8 af = *(const bf16x8*)(aP  + kk);
        bf16x8 b0 = *(const bf16x8*)(bP0 + kk);
        bf16x8 b1 = *(const bf16x8*)(bP1 + kk);
        acc[0] = __builtin_amdgcn_mfma_f32_16x16x32_bf16(af, b0, acc[0], 0, 0, 0);
        acc[1] = __builtin_amdgcn_mfma_f32_16x16x32_bf16(af, b1, acc[1], 0, 0, 0);
    }
    __syncthreads();                       // smA no longer needed -> reuse as cs
    unsigned char* cs = smA;               // [64 rows][40 B]
    #pragma unroll
    for (int nt = 0; nt < 2; ++nt)
        #pragma unroll
        for (int r = 0; r < 4; ++r)
            cs[(size_t)((wv << 4) + (kq << 2) + r) * 40 + (nt << 4) + m] =
                f2e4m3(acc[nt][r]);
    __syncthreads();
    {
        int r = tid >> 2, off = (tid & 3) << 3;
        unsigned long long v = *(const unsigned long long*)(cs + (size_t)r * 40 + off);
        *(unsigned long long*)(zo + (size_t)(row0 + r) * 256 + o0 + off) = v;
    }
}

// loss: one block (2 waves, 128 thr) per row. Wave0: DMA rows 0..32 + MFMA
// mt 0..2; wave1: DMA rows 33..64 + ctx + MFMA mt 3..4. Slots: 0 main,
// 1..64 negs, 65..79 pad (clamped). Cross-wave softmax via 4-float LDS.
#define ROWB 272
__global__ __launch_bounds__(128, 4)
void loss_mfma_kernel(const unsigned char* __restrict__ ct8,
                      const unsigned char* __restrict__ ztwk8,
                      const int* __restrict__ n0, const int* __restrict__ n1,
                      const int* __restrict__ n2, float* __restrict__ rowloss) {
    __shared__ __align__(16) unsigned char slab[65 * ROWB];   // 17680 B
    __shared__ __align__(16) unsigned char ctx_s[256];
    __shared__ float sred[2][2];
    const int tid = threadIdx.x;
    const int wv = tid >> 6, lane = tid & 63;
    const int m = lane & 15, kq = lane >> 4;

    int x = blockIdx.x;
    int k; const int* nb_base;
    if (x < 10752)      { k = 0; nb_base = n0; }
    else if (x < 20608) { k = 1; nb_base = n1; x -= 10752; }
    else                { k = 2; nb_base = n2; x -= 20608; }
    const int row = x;
    const unsigned char* flat8 = ztwk8 + (size_t)k * 10752 * 256;
    const float wk = (k == 0) ? (1.f / (3.f * 10752.f))
                   : (k == 1) ? (1.f / (3.f * 9856.f))
                              : (1.f / (3.f * 8960.f));
    const int rbase = (k == 0) ? 0 : (k == 1) ? 10752 : 20608;

    const int myidx = nb_base[((size_t)row << 6) + lane];

    // async gather: per-lane global addr, uniform LDS row base; fully unrolled
    // so readlane gets constant lanes and all DMAs are in flight together.
    if (wv == 0) {
        gload_lds4(flat8 + (size_t)row * 256 + (lane << 2), slab);          // j=0
        #pragma unroll
        for (int j = 1; j <= 32; ++j) {
            int idx = __builtin_amdgcn_readlane(myidx, j - 1);
            gload_lds4(flat8 + (size_t)idx * 256 + (lane << 2), slab + j * ROWB);
        }
    } else {
        gload_lds4(ct8 + (size_t)row * 256 + (lane << 2), ctx_s);
        #pragma unroll
        for (int j = 33; j <= 64; ++j) {
            int idx = __builtin_amdgcn_readlane(myidx, j - 1);
            gload_lds4(flat8 + (size_t)idx * 256 + (lane << 2), slab + j * ROWB);
        }
    }
    __syncthreads();   // drains vmcnt (DMA) for the whole block

    // MFMA: wave0 mt 0..2 (slots 0..47), wave1 mt 3..4 (slots 48..79, clamp)
    f32x4 acc[3] = {};
    const int mt0 = (wv == 0) ? 0 : 3;
    int soff[3];
    #pragma unroll
    for (int t = 0; t < 3; ++t) {
        int slot = ((mt0 + t) << 4) + m;
        if (slot > 64) slot = 64;
        soff[t] = slot * ROWB + (kq << 3);
    }
    const unsigned char* cp = ctx_s + (kq << 3);
    #pragma unroll
    for (int kk = 0; kk < 8; ++kk) {
        long long bfrag = *(const long long*)(cp + (kk << 5));
        #pragma unroll
        for (int t = 0; t < 3; ++t) {
            if (t < 2 || wv == 0) {
                long long af = *(const long long*)(slab + soff[t] + (kk << 5));
                acc[t] = __builtin_amdgcn_mfma_f32_16x16x32_fp8_fp8(af, bfrag, acc[t], 0, 0, 0);
            }
        }
    }

    // per-wave partial softmax (slot = mt*16 + kq*4 + r)
    float m_l = -1e30f;
    if (wv == 0) {
        #pragma unroll
        for (int t = 0; t < 3; ++t)
            #pragma unroll
            for (int r = 0; r < 4; ++r) m_l = fmaxf(m_l, acc[t][r]);
    } else {
        #pragma unroll
        for (int r = 0; r < 4; ++r) m_l = fmaxf(m_l, acc[0][r]);   // mt=3
        if (kq == 0) m_l = fmaxf(m_l, acc[1][0]);                  // slot 64
    }
    m_l = fmaxf(m_l, __shfl_xor(m_l, 16));
    m_l = fmaxf(m_l, __shfl_xor(m_l, 32));

    float s_l = 0.f;
    if (wv == 0) {
        #pragma unroll
        for (int t = 0; t < 3; ++t)
            #pragma unroll
            for (int r = 0; r < 4; ++r) s_l += __expf(acc[t][r] - m_l);
    } else {
        #pragma unroll
        for (int r = 0; r < 4; ++r) s_l += __expf(acc[0][r] - m_l);
        if (kq == 0) s_l += __expf(acc[1][0] - m_l);
    }
    s_l += __shfl_xor(s_l, 16);
    s_l += __shfl_xor(s_l, 32);

    float main_l = acc[0][0];   // valid at wv0 lane0 (slot 0)
    if (lane == 0) { sred[wv][0] = m_l; sred[wv][1] = s_l; }
    __syncthreads();
    if (tid == 0) {
        float m0 = sred[0][0], s0 = sred[0][1];
        float m1 = sred[1][0], s1 = sred[1][1];
        float mg = fmaxf(m0, m1);
        float sg = s0 * __expf(m0 - mg) + s1 * __expf(m1 - mg);
        float p0 = __expf(main_l - mg) / sg;
        rowloss[rbase + row] = -logf(p0 + 1e-11f) * wk;
    }
}

// Sum rowloss[0..29568) -> out[0]
__global__ __launch_bounds__(256)
void reduce_kernel(const float* __restrict__ rl, float* __restrict__ out) {
    float s = 0.f;
    const int stride = gridDim.x * blockDim.x;
    for (int i = blockIdx.x * blockDim.x + threadIdx.x; i < 29568; i += stride)
        s += rl[i];
    #pragma unroll
    for (int off = 32; off >= 1; off >>= 1) s += __shfl_xor(s, off);
    if ((threadIdx.x & 63) == 0) atomicAdd(out, s);
}

extern "C" void kernel_launch(void* const* d_in, const int* in_sizes, int n_in,
                              void* d_out, int out_size, void* d_ws, size_t ws_size,
                              hipStream_t stream) {
    const float* z  = (const float*)d_in[0];
    const float* c  = (const float*)d_in[1];
    const float* Wk = (const float*)d_in[2];
    const int* negs[3] = {(const int*)d_in[3], (const int*)d_in[4], (const int*)d_in[5]};
    float* out = (float*)d_out;

    // workspace: zt bf16 6.4MB | wkb bf16 384KB | ct8 fp8 3.2MB |
    // ztwk8 fp8 [3][10752][256] 8.26MB | rowloss f32 118KB
    char* p = (char*)d_ws;
    unsigned short* zt      = (unsigned short*)p;   p += (size_t)196 * 64 * 256 * 2;
    unsigned short* wkb     = (unsigned short*)p;   p += (size_t)3 * 65536 * 2;
    unsigned char*  ct8     = (unsigned char*)p;    p += (size_t)196 * 64 * 256;
    unsigned char*  ztwk8   = (unsigned char*)p;    p += (size_t)3 * 10752 * 256;
    float*          rowloss = (float*)p;

    zero_out_kernel<<<1, 1, 0, stream>>>(out);
    cast_wk_kernel<<<768, 256, 0, stream>>>(Wk, wkb);
    transpose_z_kernel<<<dim3(64, 16), 256, 0, stream>>>(z, zt);
    transpose_c8_kernel<<<dim3(64, 16), 256, 0, stream>>>(c, ct8);

    proj_mfma_kernel<<<dim3(462, 8), 256, 0, stream>>>(zt, wkb, ztwk8);

    loss_mfma_kernel<<<29568, 128, 0, stream>>>(ct8, ztwk8, negs[0], negs[1],
                                                negs[2], rowloss);
    reduce_kernel<<<32, 256, 0, stream>>>(rowloss, out);
}